// Round 17
// baseline (132.371 us; speedup 1.0000x reference)
//
#include <hip/hip_runtime.h>
#include <hip/hip_bf16.h>
#include <math.h>

#define EPSF 1e-5f
#define SELHI 0x05040100u
#define SELLO 0x07060302u

typedef __attribute__((ext_vector_type(8))) short bf16x8;
typedef __attribute__((ext_vector_type(16))) float f32x16;

// pack float -> u32 { low16 = hi-bf16 (truncated), high16 = lo-bf16 (residual) }
__device__ __forceinline__ uint32_t packsplit(float x) {
  uint32_t xb = __builtin_bit_cast(uint32_t, x);
  float hi = __builtin_bit_cast(float, xb & 0xFFFF0000u);
  float resid = x - hi;
  return __builtin_amdgcn_perm(__builtin_bit_cast(uint32_t, resid), xb, 0x07060302u);
}

// float -> bf16 round-to-nearest-even (16-bit value in low bits)
__device__ __forceinline__ uint32_t bf16rne(float x) {
  uint32_t xb = __builtin_bit_cast(uint32_t, x);
  return (xb + 0x7FFFu + ((xb >> 16) & 1u)) >> 16;
}

// DPP quad_perm [1,0,3,2]: exchange with lane^1 (VALU pipe, no DS)
__device__ __forceinline__ uint32_t dpp_xor1(uint32_t v) {
  return (uint32_t)__builtin_amdgcn_update_dpp(0, (int)v, 0xB1, 0xF, 0xF, true);
}

__device__ __forceinline__ uint4 mkfrag8(const uint32_t* p, uint32_t sel) {
  uint4 u;
  u.x = __builtin_amdgcn_perm(p[1], p[0], sel);
  u.y = __builtin_amdgcn_perm(p[3], p[2], sel);
  u.z = __builtin_amdgcn_perm(p[5], p[4], sel);
  u.w = __builtin_amdgcn_perm(p[7], p[6], sel);
  return u;
}

__device__ __forceinline__ f32x16 mf(uint4 a, uint4 b, f32x16 c) {
  return __builtin_amdgcn_mfma_f32_32x32x16_bf16(
      __builtin_bit_cast(bf16x8, a), __builtin_bit_cast(bf16x8, b), c, 0, 0, 0);
}

#define F4C(v, i) ((i) == 0 ? (v).x : (i) == 1 ? (v).y : (i) == 2 ? (v).z : (v).w)

// =====================================================================
// Kernel 0: ALL fragment precomputes in ONE dispatch (flat grid 6208).
// =====================================================================
__global__ __launch_bounds__(64) void pack_all_kernel(
    const float* __restrict__ addresses,
    const float* __restrict__ x,
    const float* __restrict__ Wk, const float* __restrict__ Wv,
    const float* __restrict__ Wq, const float* __restrict__ Wm,
    uint32_t* __restrict__ qaF, uint32_t* __restrict__ xFrag,
    uint32_t* __restrict__ wFrag, uint32_t* __restrict__ wmFrag)
{
  const int bid = blockIdx.x;
  const int lane = threadIdx.x;
  const int g32 = lane >> 5, c32 = lane & 31;

  if (bid < 4096) {                       // ---- W pack
    const int kstep = bid >> 6, ct = bid & 63;
    const int col = ct*32 + c32;
    const float* Wp; int ldb, nc;
    if (col < 512)       { Wp = Wk; ldb = 512;  nc = col; }
    else if (col < 1536) { Wp = Wv; ldb = 1024; nc = col - 512; }
    else                 { Wp = Wq; ldb = 512;  nc = col - 1536; }
    uint32_t p[8];
    #pragma unroll
    for (int j = 0; j < 8; ++j)
      p[j] = packsplit(Wp[(size_t)(kstep*16 + g32*8 + j) * ldb + nc]);
    *(uint4*)&wFrag[((size_t)(kstep*2+0)*64 + ct)*256 + lane*4] = mkfrag8(p, SELHI);
    *(uint4*)&wFrag[((size_t)(kstep*2+1)*64 + ct)*256 + lane*4] = mkfrag8(p, SELLO);
  } else if (bid < 5120) {                // ---- x pack
    const int t = bid - 4096;
    const int kstep = t >> 4, rt = t & 15;
    const float* xp = x + (size_t)(rt*32 + c32)*1024 + kstep*16 + g32*8;
    float4 f0 = *(const float4*)xp;
    float4 f1 = *(const float4*)(xp + 4);
    uint32_t p[8] = { packsplit(f0.x), packsplit(f0.y), packsplit(f0.z), packsplit(f0.w),
                      packsplit(f1.x), packsplit(f1.y), packsplit(f1.z), packsplit(f1.w) };
    *(uint4*)&xFrag[((size_t)(kstep*2+0)*16 + rt)*256 + lane*4] = mkfrag8(p, SELHI);
    *(uint4*)&xFrag[((size_t)(kstep*2+1)*16 + rt)*256 + lane*4] = mkfrag8(p, SELLO);
  } else if (bid < 5184) {                // ---- qa pack
    const int T = bid - 5120;
    #pragma unroll
    for (int ks = 0; ks < 4; ++ks) {
      const float* ap = addresses + (size_t)(T*32 + c32)*64 + ks*16 + g32*8;
      float4 f0 = *(const float4*)ap;
      float4 f1 = *(const float4*)(ap + 4);
      uint32_t qp[8] = {
        packsplit(fmaxf(f0.x,0.f)), packsplit(fmaxf(f0.y,0.f)),
        packsplit(fmaxf(f0.z,0.f)), packsplit(fmaxf(f0.w,0.f)),
        packsplit(fmaxf(f1.x,0.f)), packsplit(fmaxf(f1.y,0.f)),
        packsplit(fmaxf(f1.z,0.f)), packsplit(fmaxf(f1.w,0.f)) };
      *(uint4*)&qaF[(size_t)T*2048 + (ks*2+0)*256 + lane*4] = mkfrag8(qp, SELHI);
      *(uint4*)&qaF[(size_t)T*2048 + (ks*2+1)*256 + lane*4] = mkfrag8(qp, SELLO);
    }
  } else {                                // ---- Wm pack
    const int t = bid - 5184;
    const int ks = t >> 5, ct = t & 31;
    const int col = ct*32 + c32;
    uint32_t p[8];
    #pragma unroll
    for (int j = 0; j < 8; ++j)
      p[j] = packsplit(Wm[(size_t)(ks*16 + g32*8 + j) * 1024 + col]);
    *(uint4*)&wmFrag[((size_t)(ks*2+0)*32 + ct)*256 + lane*4] = mkfrag8(p, SELHI);
    *(uint4*)&wmFrag[((size_t)(ks*2+1)*32 + ct)*256 + lane*4] = mkfrag8(p, SELLO);
  }
}

// =====================================================================
// Kernel 1: proj via MFMA, K-split x2 (unchanged from R14).
// =====================================================================
__global__ __launch_bounds__(256) void proj_mfma_kernel(
    const uint32_t* __restrict__ xFrag, const uint32_t* __restrict__ wFrag,
    const float* __restrict__ bk, const float* __restrict__ bv,
    const float* __restrict__ bq, float* __restrict__ proj)
{
  __shared__ float red[2][64][16];
  const int tid = threadIdx.x;
  const int wave = tid >> 6, lane = tid & 63;
  const int g32 = lane >> 5, c32 = lane & 31;
  const int tile = blockIdx.x*2 + (wave & 1);
  const int khalf = wave >> 1;
  const int rt = tile >> 6, ct = tile & 63;

  f32x16 acc;
  #pragma unroll
  for (int r = 0; r < 16; ++r) acc[r] = 0.f;

  const uint32_t* xb = xFrag + (size_t)rt*256 + lane*4;
  const uint32_t* wb = wFrag + (size_t)ct*256 + lane*4;

  #pragma unroll 2
  for (int k8 = 0; k8 < 32; ++k8) {
    const int ks = khalf*32 + k8;
    uint4 Ah = *(const uint4*)(xb + (size_t)(ks*2+0)*16*256);
    uint4 Al = *(const uint4*)(xb + (size_t)(ks*2+1)*16*256);
    uint4 Bh = *(const uint4*)(wb + (size_t)(ks*2+0)*64*256);
    uint4 Bl = *(const uint4*)(wb + (size_t)(ks*2+1)*64*256);
    acc = mf(Ah, Bh, acc);
    acc = mf(Ah, Bl, acc);
    acc = mf(Al, Bh, acc);
  }

  if (khalf == 1) {
    #pragma unroll
    for (int r = 0; r < 16; ++r) red[wave & 1][lane][r] = acc[r];
  }
  __syncthreads();
  if (khalf == 0) {
    const int col = ct*32 + c32;
    const float* bias; int nc, relu;
    if (col < 512)       { bias = bk; nc = col;        relu = 1; }
    else if (col < 1536) { bias = bv; nc = col - 512;  relu = 0; }
    else                 { bias = bq; nc = col - 1536; relu = 1; }
    const float bvv = bias[nc];
    #pragma unroll
    for (int r = 0; r < 16; ++r) {
      const int m = rt*32 + (r & 3) + 8*(r >> 2) + 4*g32;
      float v = acc[r] + red[wave & 1][lane][r] + bvv;
      if (relu) v = fmaxf(v, 0.f);
      proj[(size_t)m * 2048 + col] = v;
    }
  }
}

// =====================================================================
// Kernel 2: fused memory kernel, R16.
//   vs R15: pk tiles stored as ROW-PAIR-MERGED u32 (pkP[rp][col] =
//   bf16(row 2rp) | bf16(row 2rp+1)<<16). ELEM merges adjacent rows
//   via DPP quad_perm xor1 (VALU pipe); phase-D reads become single
//   ds_read_b32 (128 -> 32 DS reads per superstep). XOR swizzle
//   col ^= (rp&7)<<2 on both sides. Numerics bit-identical to R15.
// =====================================================================
__global__ __launch_bounds__(256, 2) void fused_mem_kernel(
    const float* __restrict__ memories,   // [512][2048][64]
    const float* __restrict__ addresses,  // [2048][64]
    const float* __restrict__ proj,       // [512][2048] = fk|v|fq
    const uint32_t* __restrict__ qaF,     // [64][8][64][4] qa fragments
    uint32_t* __restrict__ attnHi,        // [512][256] u32
    uint32_t* __restrict__ attnLo)        // [512][256]
{
  // 80 KB arena (u32 indices):
  //  [0,2048)       fkFrag        (epilogue: n2stage/norm2/den2 overlay)
  //  [2048,4096)    vFrag
  //  [4096,12288)   pk: 4 waves x { pkF[16][64], pkN[16][64] } u32 pairs
  //  [12288,20480)  qabuf: 4 waves x 2048 u32 (8 KB qa staging)
  __shared__ uint32_t SH[20480];

  const int b = blockIdx.x, tid = threadIdx.x;
  const int wave = tid >> 6, lane = tid & 63;
  const int g32 = lane >> 5, c32 = lane & 31;

  uint32_t* fkFrag = SH;
  uint32_t* vFrag  = SH + 2048;
  uint32_t* pkbase = SH + 4096;
  uint32_t* pkF = pkbase + wave * 2048;   // [16][64] u32 row-pairs
  uint32_t* pkN = pkF + 1024;
  uint32_t* qabuf = SH + 12288 + wave * 2048;

  // ---- stage proj row (pbuf overlays pk region) ----
  float* pbuf = (float*)pkbase;
  {
    const float* prow = proj + (size_t)b * 2048;
    *(float4*)&pbuf[tid*8]   = *(const float4*)&prow[tid*8];
    *(float4*)&pbuf[tid*8+4] = *(const float4*)&prow[tid*8+4];
  }
  __syncthreads();

  // ---- one-time fragment packing (wave w: kstep w, e-tile w) ----
  {
    const int ks = wave;
    float4 f0 = *(const float4*)&pbuf[c32*64 + ks*16 + g32*8];
    float4 f1 = *(const float4*)&pbuf[c32*64 + ks*16 + g32*8 + 4];
    uint32_t p[8] = { packsplit(f0.x), packsplit(f0.y), packsplit(f0.z), packsplit(f0.w),
                      packsplit(f1.x), packsplit(f1.y), packsplit(f1.z), packsplit(f1.w) };
    *(uint4*)&fkFrag[((ks*2+0)*64 + lane)*4] = mkfrag8(p, SELHI);
    *(uint4*)&fkFrag[((ks*2+1)*64 + lane)*4] = mkfrag8(p, SELLO);
    const int t = wave;
    uint32_t q[8];
    #pragma unroll
    for (int j = 0; j < 8; ++j) {
      int h = (g32*8 + j) & 7;
      q[j] = packsplit(pbuf[512 + h*128 + t*32 + c32]);
    }
    *(uint4*)&vFrag[((t*2+0)*64 + lane)*4] = mkfrag8(q, SELHI);
    *(uint4*)&vFrag[((t*2+1)*64 + lane)*4] = mkfrag8(q, SELLO);
  }
  __syncthreads();

  f32x16 Zv;
  #pragma unroll
  for (int r = 0; r < 16; ++r) Zv[r] = 0.f;
  f32x16 aD00 = Zv, aD01 = Zv, aD10 = Zv, aD11 = Zv;
  float n2a[32];
  #pragma unroll
  for (int k = 0; k < 32; ++k) n2a[k] = 0.f;

  const float* aRow0 = addresses + (size_t)(wave*512 + c32) * 64;
  const float* mRow0 = memories + ((size_t)b*2048 + wave*512 + c32) * 64;

  // stage qa fragments for tile T into this wave's LDS slot (no VGPRs)
  auto stage_qa = [&](int T) {
    const uint32_t* src = qaF + (size_t)T*2048 + lane*4;
    #pragma unroll
    for (int j = 0; j < 8; ++j)
      __builtin_amdgcn_global_load_lds(
        (const __attribute__((address_space(1))) uint32_t*)(src + j*256),
        (__attribute__((address_space(3))) uint32_t*)(qabuf + j*256), 16, 0, 0);
    asm volatile("" ::: "memory");
  };

  // phase D: single b32 reads of row-pair-merged operands.
  auto do_mfma = [&](int base) {
    uint32_t f0[4], f1[4], n0[4], n1[4];
    #pragma unroll
    for (int e = 0; e < 4; ++e) {
      const int rp = (base >> 1) + g32*4 + e;
      const int sw = (rp & 7) << 2;
      const int c0 = (c32 ^ sw);
      const int c1 = ((32 + c32) ^ sw);
      f0[e] = pkF[rp*64 + c0];
      f1[e] = pkF[rp*64 + c1];
      n0[e] = pkN[rp*64 + c0];
      n1[e] = pkN[rp*64 + c1];
    }
    uint4 A0 = make_uint4(f0[0], f0[1], f0[2], f0[3]);
    uint4 A1 = make_uint4(f1[0], f1[1], f1[2], f1[3]);
    uint4 B0 = make_uint4(n0[0], n0[1], n0[2], n0[3]);
    uint4 B1 = make_uint4(n1[0], n1[1], n1[2], n1[3]);
    aD00 = mf(A0, B0, aD00);
    aD01 = mf(A0, B1, aD01);
    aD10 = mf(A1, B0, aD10);
    aD11 = mf(A1, B1, aD11);
  };

  // B-MFMAs consuming the LDS-staged qa fragments (pure LDS reads)
#define QALDS_B(ACC) do {                                              \
    _Pragma("unroll")                                                  \
    for (int ks = 0; ks < 4; ++ks) {                                   \
      uint4 qh_ = *(uint4*)&qabuf[(ks*2+0)*256 + lane*4];              \
      uint4 ql_ = *(uint4*)&qabuf[(ks*2+1)*256 + lane*4];              \
      uint4 Ah_ = *(uint4*)&fkFrag[((ks*2+0)*64 + lane)*4];            \
      uint4 Al_ = *(uint4*)&fkFrag[((ks*2+1)*64 + lane)*4];            \
      ACC = mf(Ah_, qh_, ACC); ACC = mf(Ah_, ql_, ACC); ACC = mf(Al_, qh_, ACC); \
    } } while(0)

  // elementwise for one 32-col half; merges adjacent rows' bf16 via
  // DPP xor1, even lanes write uint4 row-pairs to pk tiles.
#define ELEM(T2, ACU, ACW) do {                                        \
    const int rp_ = c32 >> 1;                                          \
    const int odd_ = c32 & 1;                                          \
    const int sw_ = (rp_ & 7) << 2;                                    \
    uint32_t* rowF_ = pkF + rp_*64;                                    \
    uint32_t* rowN_ = pkN + rp_*64;                                    \
    _Pragma("unroll")                                                  \
    for (int rq = 0; rq < 4; ++rq) {                                   \
      uint32_t mF_[4], mN_[4];                                         \
      _Pragma("unroll")                                                \
      for (int i = 0; i < 4; ++i) {                                    \
        const int r = rq*4 + i;                                        \
        float upd = ACU[r];                                            \
        float wx  = ACW[r];                                            \
        float wp  = __builtin_amdgcn_rcpf(1.f + __expf(-wx));          \
        float mv  = F4C(M_[(T2)*4 + rq], i);                           \
        float av  = F4C(E_[rq & 1], i);                                \
        float nm  = fmaf(wp, upd - mv, mv);                            \
        float fv  = fmaxf(nm + av, 0.f);                               \
        n2a[(T2)*16 + r] += fv;                                        \
        uint32_t pn_ = bf16rne(nm);                                    \
        uint32_t pf_ = bf16rne(fv);                                    \
        uint32_t qn_ = dpp_xor1(pn_);                                  \
        uint32_t qf_ = dpp_xor1(pf_);                                  \
        mN_[i] = odd_ ? (qn_ | (pn_ << 16)) : (pn_ | (qn_ << 16));     \
        mF_[i] = odd_ ? (qf_ | (pf_ << 16)) : (pf_ | (qf_ << 16));     \
      }                                                                \
      if (rq == 1) { E_[0] = *(const float4*)(ap0 + (T2)*32 + 16 + g32*4);      \
                     E_[1] = *(const float4*)(ap0 + (T2)*32 + 16 + g32*4 + 8); }\
      const int col = (32*(T2) + 8*rq + 4*g32) ^ sw_;                  \
      if (!odd_) {                                                     \
        *(uint4*)&rowF_[col] = make_uint4(mF_[0], mF_[1], mF_[2], mF_[3]); \
        *(uint4*)&rowN_[col] = make_uint4(mN_[0], mN_[1], mN_[2], mN_[3]); \
      }                                                                \
    } } while(0)

  // ---- prologue: stage qa(0), B(0), stage qa(1), M(0) ----
  f32x16 aBcur = Zv, aBnext;
  float4 M_[8];
  stage_qa(wave*16 + 0);
  asm volatile("s_waitcnt vmcnt(0)" ::: "memory");
  __builtin_amdgcn_sched_barrier(0);
  QALDS_B(aBcur);
  stage_qa(wave*16 + 1);
  #pragma unroll
  for (int k = 0; k < 8; ++k) M_[k] = *(const float4*)(mRow0 + k*8 + g32*4);

  #pragma unroll 1
  for (int ss = 0; ss < 16; ++ss) {
    asm volatile("" ::: "memory");

    // ---- 1. finish B(ss): S, den; rden folded into S-fragment ----
    float s0 = aBcur[0], s1 = aBcur[1], s2 = aBcur[2], s3 = aBcur[3];
    float own = (s0 + s1) + (s2 + s3);
    float den = own + __shfl_xor(own, 32) + EPSF;
    float rden = __builtin_amdgcn_rcpf(den);
    float p0 = __shfl_xor(s0, 32), p1 = __shfl_xor(s1, 32),
          p2 = __shfl_xor(s2, 32), p3 = __shfl_xor(s3, 32);
    float rm = (g32 == 0) ? rden : 0.f;
    uint32_t sp[8] = { packsplit(s0*rm), packsplit(s1*rm), packsplit(s2*rm), packsplit(s3*rm),
                       packsplit(p0*rm), packsplit(p1*rm), packsplit(p2*rm), packsplit(p3*rm) };
    uint4 Sh = mkfrag8(sp, SELHI), Sl = mkfrag8(sp, SELLO);

    // ---- 2. C-MFMAs, first half (e-tiles 0 and 2) ----
    f32x16 aC0 = Zv, aC2 = Zv;
    {
      uint4 Vh, Vl;
      Vh = *(uint4*)&vFrag[(0*64 + lane)*4]; Vl = *(uint4*)&vFrag[(1*64 + lane)*4];
      aC0 = mf(Vh, Sh, aC0); aC0 = mf(Vh, Sl, aC0); aC0 = mf(Vl, Sh, aC0);
      Vh = *(uint4*)&vFrag[(4*64 + lane)*4]; Vl = *(uint4*)&vFrag[(5*64 + lane)*4];
      aC2 = mf(Vh, Sh, aC2); aC2 = mf(Vh, Sl, aC2); aC2 = mf(Vl, Sh, aC2);
    }

    // ---- 3. pipeline: B(ss+1) from LDS-staged qa; then stage qa(ss+2) ----
    aBnext = Zv;
    if (ss < 15) QALDS_B(aBnext);
    if (ss < 14) stage_qa(wave*16 + ss + 2);

    // ---- 4. ELEM half 0 ----
    const float* ap0 = aRow0 + (size_t)ss * 2048;
    float4 E_[2];
    E_[0] = *(const float4*)(ap0 + g32*4);
    E_[1] = *(const float4*)(ap0 + g32*4 + 8);
    ELEM(0, aC0, aC2);

    // ---- 5. C-MFMAs, second half (e-tiles 1 and 3) ----
    f32x16 aC1 = Zv, aC3 = Zv;
    {
      uint4 Vh, Vl;
      Vh = *(uint4*)&vFrag[(2*64 + lane)*4]; Vl = *(uint4*)&vFrag[(3*64 + lane)*4];
      aC1 = mf(Vh, Sh, aC1); aC1 = mf(Vh, Sl, aC1); aC1 = mf(Vl, Sh, aC1);
      Vh = *(uint4*)&vFrag[(6*64 + lane)*4]; Vl = *(uint4*)&vFrag[(7*64 + lane)*4];
      aC3 = mf(Vh, Sh, aC3); aC3 = mf(Vh, Sl, aC3); aC3 = mf(Vl, Sh, aC3);
    }

    // ---- 6. M_[0..3] <- ss+1 (HBM stream) ----
    if (ss < 15) {
      const float* mp = mRow0 + (size_t)(ss+1) * 2048;
      #pragma unroll
      for (int k = 0; k < 4; ++k) M_[k] = *(const float4*)(mp + k*8 + g32*4);
    }

    // ---- 7. ELEM half 1 ----
    E_[0] = *(const float4*)(ap0 + 32 + g32*4);
    E_[1] = *(const float4*)(ap0 + 32 + g32*4 + 8);
    ELEM(1, aC1, aC3);

    // ---- 8. M_[4..7] <- ss+1 ----
    if (ss < 15) {
      const float* mp = mRow0 + (size_t)(ss+1) * 2048;
      #pragma unroll
      for (int k = 4; k < 8; ++k) M_[k] = *(const float4*)(mp + k*8 + g32*4);
    }

    // ---- 9. phase D: both 16-row chunks (b32 DS reads + MFMA) ----
    asm volatile("" ::: "memory");
    do_mfma(0);
    do_mfma(16);

    aBcur = aBnext;
  }

  // ================= epilogue =================
  __syncthreads();

  float* n2stageF = (float*)SH;            // [4][64]
  float* norm2F   = ((float*)SH) + 256;    // [64]
  float* den2F    = ((float*)SH) + 320;    // [8]
  float* stageF   = (float*)pkbase;        // [4][16][66] (pk+qa overlay)
  const float* fqg = proj + (size_t)b * 2048 + 1536;

  #pragma unroll
  for (int k = 0; k < 32; ++k) {
    float v = n2a[k];
    v += __shfl_xor(v, 1); v += __shfl_xor(v, 2); v += __shfl_xor(v, 4);
    v += __shfl_xor(v, 8); v += __shfl_xor(v, 16);
    n2a[k] = v;
  }
  if (c32 == 0) {
    #pragma unroll
    for (int t2 = 0; t2 < 2; ++t2)
      #pragma unroll
      for (int r = 0; r < 16; ++r) {
        const int j = 32*t2 + 8*(r>>2) + (r&3) + 4*g32;
        n2stageF[wave*64 + j] = n2a[t2*16 + r];
      }
  }
  __syncthreads();
  if (tid < 64)
    norm2F[tid] = (n2stageF[tid] + n2stageF[64+tid]) + (n2stageF[128+tid] + n2stageF[192+tid]);
  __syncthreads();
  if (tid < 8) {
    float s = 0.f;
    for (int d = 0; d < 64; ++d) s = fmaf(fqg[tid*64 + d], norm2F[d], s);
    den2F[tid] = s + EPSF;
  }

  const int hh = tid >> 5;
  const int ee = (tid & 31) * 2;
  float num2a = 0.f, num2b = 0.f;
  #pragma unroll
  for (int p = 0; p < 4; ++p) {
    const int ti = p >> 1, rh = p & 1;
    #pragma unroll
    for (int q = 0; q < 8; ++q) {
      const int rr = (q & 3) + 8*((q >> 2) & 1) + 4*g32;
      const int r = rh*8 + q;
      float v0 = (ti == 0) ? aD00[r] : aD10[r];
      float v1 = (ti == 0) ? aD01[r] : aD11[r];
      stageF[wave*1056 + rr*66 + c32]      = v0;
      stageF[wave*1056 + rr*66 + 32 + c32] = v1;
    }
    __syncthreads();
    #pragma unroll 8
    for (int dl = 0; dl < 16; ++dl) {
      float2 q0 = *(const float2*)&stageF[0*1056 + dl*66 + ee];
      float2 q1 = *(const float2*)&stageF[1*1056 + dl*66 + ee];
      float2 q2 = *(const float2*)&stageF[2*1056 + dl*66 + ee];
      float2 q3 = *(const float2*)&stageF[3*1056 + dl*66 + ee];
      float v0 = (q0.x + q1.x) + (q2.x + q3.x);
      float v1 = (q0.y + q1.y) + (q2.y + q3.y);
      float fv = fqg[hh*64 + p*16 + dl];
      num2a = fmaf(fv, v0, num2a);
      num2b = fmaf(fv, v1, num2b);
    }
    __syncthreads();
  }
  float rd2 = __builtin_amdgcn_rcpf(den2F[hh]);
  {
    uint32_t pa = packsplit(num2a * rd2);
    uint32_t pb = packsplit(num2b * rd2);
    const int w32 = b*256 + hh*32 + (ee >> 1);
    attnHi[w32] = __builtin_amdgcn_perm(pb, pa, SELHI);
    attnLo[w32] = __builtin_amdgcn_perm(pb, pa, SELLO);
  }
#undef ELEM
#undef QALDS_B
}

// =====================================================================
// Kernel 3: out = attn @ Wm + bm via MFMA (unchanged from R14).
// =====================================================================
__global__ __launch_bounds__(256) void out_mfma_kernel(
    const uint32_t* __restrict__ attnHi, const uint32_t* __restrict__ attnLo,
    const uint32_t* __restrict__ wmFrag, const float* __restrict__ bm,
    float* __restrict__ out)
{
  __shared__ float red[3][64][16];
  const int tid = threadIdx.x;
  const int wave = tid >> 6, lane = tid & 63;
  const int g32 = lane >> 5, c32 = lane & 31;
  const int rt = blockIdx.x >> 5, ct = blockIdx.x & 31;

  f32x16 acc;
  #pragma unroll
  for (int r = 0; r < 16; ++r) acc[r] = 0.f;

  const uint32_t* ah = attnHi + (size_t)(rt*32 + c32)*256 + g32*4;
  const uint32_t* al = attnLo + (size_t)(rt*32 + c32)*256 + g32*4;
  const uint32_t* wb = wmFrag + (size_t)ct*256 + lane*4;

  #pragma unroll
  for (int k8 = 0; k8 < 8; ++k8) {
    const int ks = wave*8 + k8;
    uint4 Ah = *(const uint4*)(ah + ks*8);
    uint4 Al = *(const uint4*)(al + ks*8);
    uint4 Bh = *(const uint4*)(wb + (size_t)(ks*2+0)*32*256);
    uint4 Bl = *(const uint4*)(wb + (size_t)(ks*2+1)*32*256);
    acc = mf(Ah, Bh, acc);
    acc = mf(Ah, Bl, acc);
    acc = mf(Al, Bh, acc);
  }

  if (wave) {
    #pragma unroll
    for (int r = 0; r < 16; ++r) red[wave-1][lane][r] = acc[r];
  }
  __syncthreads();
  if (wave == 0) {
    const int col = ct*32 + c32;
    const float bvv = bm[col];
    #pragma unroll
    for (int r = 0; r < 16; ++r) {
      const int m = rt*32 + (r & 3) + 8*(r >> 2) + 4*g32;
      float v = acc[r] + (red[0][lane][r] + red[1][lane][r]) + red[2][lane][r] + bvv;
      out[(size_t)m * 1024 + col] = v;
    }
  }
}

extern "C" void kernel_launch(void* const* d_in, const int* in_sizes, int n_in,
                              void* d_out, int out_size, void* d_ws, size_t ws_size,
                              hipStream_t stream)
{
  const float* x    = (const float*)d_in[0];
  const float* mem  = (const float*)d_in[1];
  const float* addr = (const float*)d_in[2];
  const float* Wk   = (const float*)d_in[3];
  const float* bk   = (const float*)d_in[4];
  const float* Wv   = (const float*)d_in[5];
  const float* bv   = (const float*)d_in[6];
  const float* Wq   = (const float*)d_in[7];
  const float* bq   = (const float*)d_in[8];
  const float* Wm   = (const float*)d_in[9];
  const float* bm   = (const float*)d_in[10];
  float* out  = (float*)d_out;
  float* ws   = (float*)d_ws;
  float* proj = ws;                                         // 4 MB
  uint32_t* qaF    = (uint32_t*)(proj + (size_t)512*2048);  // 0.5 MB
  uint32_t* wFrag  = qaF + 131072;                          // 8 MB
  uint32_t* xFrag  = wFrag + 2097152;                       // 2 MB
  uint32_t* wmFrag = xFrag + 524288;                        // 2 MB
  uint32_t* attnHi = wmFrag + 524288;                       // 0.5 MB
  uint32_t* attnLo = attnHi + 131072;                       // 0.5 MB

  hipLaunchKernelGGL(pack_all_kernel, dim3(6208), dim3(64), 0, stream,
                     addr, x, Wk, Wv, Wq, Wm, qaF, xFrag, wFrag, wmFrag);
  hipLaunchKernelGGL(proj_mfma_kernel, dim3(512), dim3(256), 0, stream,
                     xFrag, wFrag, bk, bv, bq, proj);
  hipLaunchKernelGGL(fused_mem_kernel, dim3(512), dim3(256), 0, stream,
                     mem, addr, proj, qaF, attnHi, attnLo);
  hipLaunchKernelGGL(out_mfma_kernel, dim3(512), dim3(256), 0, stream,
                     attnHi, attnLo, wmFrag, bm, out);
}

// Round 18
// 120.773 us; speedup vs baseline: 1.0960x; 1.0960x over previous
//
#include <hip/hip_runtime.h>
#include <hip/hip_bf16.h>
#include <math.h>

#define EPSF 1e-5f
#define SELHI 0x05040100u
#define SELLO 0x07060302u

typedef __attribute__((ext_vector_type(8))) short bf16x8;
typedef __attribute__((ext_vector_type(16))) float f32x16;

// pack float -> u32 { low16 = hi-bf16 (truncated), high16 = lo-bf16 (residual) }
__device__ __forceinline__ uint32_t packsplit(float x) {
  uint32_t xb = __builtin_bit_cast(uint32_t, x);
  float hi = __builtin_bit_cast(float, xb & 0xFFFF0000u);
  float resid = x - hi;
  return __builtin_amdgcn_perm(__builtin_bit_cast(uint32_t, resid), xb, 0x07060302u);
}

// float -> bf16 round-to-nearest-even (16-bit value in low bits)
__device__ __forceinline__ uint32_t bf16rne(float x) {
  uint32_t xb = __builtin_bit_cast(uint32_t, x);
  return (xb + 0x7FFFu + ((xb >> 16) & 1u)) >> 16;
}

__device__ __forceinline__ uint4 mkfrag8(const uint32_t* p, uint32_t sel) {
  uint4 u;
  u.x = __builtin_amdgcn_perm(p[1], p[0], sel);
  u.y = __builtin_amdgcn_perm(p[3], p[2], sel);
  u.z = __builtin_amdgcn_perm(p[5], p[4], sel);
  u.w = __builtin_amdgcn_perm(p[7], p[6], sel);
  return u;
}

__device__ __forceinline__ f32x16 mf(uint4 a, uint4 b, f32x16 c) {
  return __builtin_amdgcn_mfma_f32_32x32x16_bf16(
      __builtin_bit_cast(bf16x8, a), __builtin_bit_cast(bf16x8, b), c, 0, 0, 0);
}

#define F4C(v, i) ((i) == 0 ? (v).x : (i) == 1 ? (v).y : (i) == 2 ? (v).z : (v).w)

// =====================================================================
// Kernel 0: ALL fragment precomputes in ONE dispatch (flat grid 6208).
// =====================================================================
__global__ __launch_bounds__(64) void pack_all_kernel(
    const float* __restrict__ addresses,
    const float* __restrict__ x,
    const float* __restrict__ Wk, const float* __restrict__ Wv,
    const float* __restrict__ Wq, const float* __restrict__ Wm,
    uint32_t* __restrict__ qaF, uint32_t* __restrict__ xFrag,
    uint32_t* __restrict__ wFrag, uint32_t* __restrict__ wmFrag)
{
  const int bid = blockIdx.x;
  const int lane = threadIdx.x;
  const int g32 = lane >> 5, c32 = lane & 31;

  if (bid < 4096) {                       // ---- W pack
    const int kstep = bid >> 6, ct = bid & 63;
    const int col = ct*32 + c32;
    const float* Wp; int ldb, nc;
    if (col < 512)       { Wp = Wk; ldb = 512;  nc = col; }
    else if (col < 1536) { Wp = Wv; ldb = 1024; nc = col - 512; }
    else                 { Wp = Wq; ldb = 512;  nc = col - 1536; }
    uint32_t p[8];
    #pragma unroll
    for (int j = 0; j < 8; ++j)
      p[j] = packsplit(Wp[(size_t)(kstep*16 + g32*8 + j) * ldb + nc]);
    *(uint4*)&wFrag[((size_t)(kstep*2+0)*64 + ct)*256 + lane*4] = mkfrag8(p, SELHI);
    *(uint4*)&wFrag[((size_t)(kstep*2+1)*64 + ct)*256 + lane*4] = mkfrag8(p, SELLO);
  } else if (bid < 5120) {                // ---- x pack
    const int t = bid - 4096;
    const int kstep = t >> 4, rt = t & 15;
    const float* xp = x + (size_t)(rt*32 + c32)*1024 + kstep*16 + g32*8;
    float4 f0 = *(const float4*)xp;
    float4 f1 = *(const float4*)(xp + 4);
    uint32_t p[8] = { packsplit(f0.x), packsplit(f0.y), packsplit(f0.z), packsplit(f0.w),
                      packsplit(f1.x), packsplit(f1.y), packsplit(f1.z), packsplit(f1.w) };
    *(uint4*)&xFrag[((size_t)(kstep*2+0)*16 + rt)*256 + lane*4] = mkfrag8(p, SELHI);
    *(uint4*)&xFrag[((size_t)(kstep*2+1)*16 + rt)*256 + lane*4] = mkfrag8(p, SELLO);
  } else if (bid < 5184) {                // ---- qa pack
    const int T = bid - 5120;
    #pragma unroll
    for (int ks = 0; ks < 4; ++ks) {
      const float* ap = addresses + (size_t)(T*32 + c32)*64 + ks*16 + g32*8;
      float4 f0 = *(const float4*)ap;
      float4 f1 = *(const float4*)(ap + 4);
      uint32_t qp[8] = {
        packsplit(fmaxf(f0.x,0.f)), packsplit(fmaxf(f0.y,0.f)),
        packsplit(fmaxf(f0.z,0.f)), packsplit(fmaxf(f0.w,0.f)),
        packsplit(fmaxf(f1.x,0.f)), packsplit(fmaxf(f1.y,0.f)),
        packsplit(fmaxf(f1.z,0.f)), packsplit(fmaxf(f1.w,0.f)) };
      *(uint4*)&qaF[(size_t)T*2048 + (ks*2+0)*256 + lane*4] = mkfrag8(qp, SELHI);
      *(uint4*)&qaF[(size_t)T*2048 + (ks*2+1)*256 + lane*4] = mkfrag8(qp, SELLO);
    }
  } else {                                // ---- Wm pack
    const int t = bid - 5184;
    const int ks = t >> 5, ct = t & 31;
    const int col = ct*32 + c32;
    uint32_t p[8];
    #pragma unroll
    for (int j = 0; j < 8; ++j)
      p[j] = packsplit(Wm[(size_t)(ks*16 + g32*8 + j) * 1024 + col]);
    *(uint4*)&wmFrag[((size_t)(ks*2+0)*32 + ct)*256 + lane*4] = mkfrag8(p, SELHI);
    *(uint4*)&wmFrag[((size_t)(ks*2+1)*32 + ct)*256 + lane*4] = mkfrag8(p, SELLO);
  }
}

// =====================================================================
// Kernel 1: proj via MFMA, K-split x2.
// =====================================================================
__global__ __launch_bounds__(256) void proj_mfma_kernel(
    const uint32_t* __restrict__ xFrag, const uint32_t* __restrict__ wFrag,
    const float* __restrict__ bk, const float* __restrict__ bv,
    const float* __restrict__ bq, float* __restrict__ proj)
{
  __shared__ float red[2][64][16];
  const int tid = threadIdx.x;
  const int wave = tid >> 6, lane = tid & 63;
  const int g32 = lane >> 5, c32 = lane & 31;
  const int tile = blockIdx.x*2 + (wave & 1);
  const int khalf = wave >> 1;
  const int rt = tile >> 6, ct = tile & 63;

  f32x16 acc;
  #pragma unroll
  for (int r = 0; r < 16; ++r) acc[r] = 0.f;

  const uint32_t* xb = xFrag + (size_t)rt*256 + lane*4;
  const uint32_t* wb = wFrag + (size_t)ct*256 + lane*4;

  #pragma unroll 2
  for (int k8 = 0; k8 < 32; ++k8) {
    const int ks = khalf*32 + k8;
    uint4 Ah = *(const uint4*)(xb + (size_t)(ks*2+0)*16*256);
    uint4 Al = *(const uint4*)(xb + (size_t)(ks*2+1)*16*256);
    uint4 Bh = *(const uint4*)(wb + (size_t)(ks*2+0)*64*256);
    uint4 Bl = *(const uint4*)(wb + (size_t)(ks*2+1)*64*256);
    acc = mf(Ah, Bh, acc);
    acc = mf(Ah, Bl, acc);
    acc = mf(Al, Bh, acc);
  }

  if (khalf == 1) {
    #pragma unroll
    for (int r = 0; r < 16; ++r) red[wave & 1][lane][r] = acc[r];
  }
  __syncthreads();
  if (khalf == 0) {
    const int col = ct*32 + c32;
    const float* bias; int nc, relu;
    if (col < 512)       { bias = bk; nc = col;        relu = 1; }
    else if (col < 1536) { bias = bv; nc = col - 512;  relu = 0; }
    else                 { bias = bq; nc = col - 1536; relu = 1; }
    const float bvv = bias[nc];
    #pragma unroll
    for (int r = 0; r < 16; ++r) {
      const int m = rt*32 + (r & 3) + 8*(r >> 2) + 4*g32;
      float v = acc[r] + red[wave & 1][lane][r] + bvv;
      if (relu) v = fmaxf(v, 0.f);
      proj[(size_t)m * 2048 + col] = v;
    }
  }
}

// =====================================================================
// Kernel 2: fused memory kernel (R15 exact — best known configuration).
//   qa fragments staged into per-wave LDS via global_load_lds; pk tiles
//   [32][64] u16 with XOR swizzle (col ^= (row&7)<<3); 80 KB arena,
//   2 blocks/CU, no spill.
// =====================================================================
__global__ __launch_bounds__(256, 2) void fused_mem_kernel(
    const float* __restrict__ memories,   // [512][2048][64]
    const float* __restrict__ addresses,  // [2048][64]
    const float* __restrict__ proj,       // [512][2048] = fk|v|fq
    const uint32_t* __restrict__ qaF,     // [64][8][64][4] qa fragments
    uint32_t* __restrict__ attnHi,        // [512][256] u32
    uint32_t* __restrict__ attnLo)        // [512][256]
{
  // 80 KB arena (u32 indices):
  //  [0,2048)       fkFrag        (epilogue: n2stage/norm2/den2 overlay)
  //  [2048,4096)    vFrag
  //  [4096,12288)   pk: 4 waves x { pF16[32][64], pN16[32][64] } u16
  //  [12288,20480)  qabuf: 4 waves x 2048 u32 (8 KB qa staging)
  __shared__ uint32_t SH[20480];

  const int b = blockIdx.x, tid = threadIdx.x;
  const int wave = tid >> 6, lane = tid & 63;
  const int g32 = lane >> 5, c32 = lane & 31;

  uint32_t* fkFrag = SH;
  uint32_t* vFrag  = SH + 2048;
  uint32_t* pkbase = SH + 4096;
  unsigned short* pF16 = (unsigned short*)(pkbase + wave * 2048);  // [32][64]
  unsigned short* pN16 = pF16 + 2048;
  uint32_t* qabuf = SH + 12288 + wave * 2048;

  // ---- stage proj row (pbuf overlays pk region) ----
  float* pbuf = (float*)pkbase;
  {
    const float* prow = proj + (size_t)b * 2048;
    *(float4*)&pbuf[tid*8]   = *(const float4*)&prow[tid*8];
    *(float4*)&pbuf[tid*8+4] = *(const float4*)&prow[tid*8+4];
  }
  __syncthreads();

  // ---- one-time fragment packing (wave w: kstep w, e-tile w) ----
  {
    const int ks = wave;
    float4 f0 = *(const float4*)&pbuf[c32*64 + ks*16 + g32*8];
    float4 f1 = *(const float4*)&pbuf[c32*64 + ks*16 + g32*8 + 4];
    uint32_t p[8] = { packsplit(f0.x), packsplit(f0.y), packsplit(f0.z), packsplit(f0.w),
                      packsplit(f1.x), packsplit(f1.y), packsplit(f1.z), packsplit(f1.w) };
    *(uint4*)&fkFrag[((ks*2+0)*64 + lane)*4] = mkfrag8(p, SELHI);
    *(uint4*)&fkFrag[((ks*2+1)*64 + lane)*4] = mkfrag8(p, SELLO);
    const int t = wave;
    uint32_t q[8];
    #pragma unroll
    for (int j = 0; j < 8; ++j) {
      int h = (g32*8 + j) & 7;
      q[j] = packsplit(pbuf[512 + h*128 + t*32 + c32]);
    }
    *(uint4*)&vFrag[((t*2+0)*64 + lane)*4] = mkfrag8(q, SELHI);
    *(uint4*)&vFrag[((t*2+1)*64 + lane)*4] = mkfrag8(q, SELLO);
  }
  __syncthreads();

  f32x16 Zv;
  #pragma unroll
  for (int r = 0; r < 16; ++r) Zv[r] = 0.f;
  f32x16 aD00 = Zv, aD01 = Zv, aD10 = Zv, aD11 = Zv;
  float n2a[32];
  #pragma unroll
  for (int k = 0; k < 32; ++k) n2a[k] = 0.f;

  const float* aRow0 = addresses + (size_t)(wave*512 + c32) * 64;
  const float* mRow0 = memories + ((size_t)b*2048 + wave*512 + c32) * 64;

  // stage qa fragments for tile T into this wave's LDS slot (no VGPRs)
  auto stage_qa = [&](int T) {
    const uint32_t* src = qaF + (size_t)T*2048 + lane*4;
    #pragma unroll
    for (int j = 0; j < 8; ++j)
      __builtin_amdgcn_global_load_lds(
        (const __attribute__((address_space(1))) uint32_t*)(src + j*256),
        (__attribute__((address_space(3))) uint32_t*)(qabuf + j*256), 16, 0, 0);
    asm volatile("" ::: "memory");
  };

  // phase D: single-bf16 operands from XOR-swizzled [32][64] u16 tiles.
  auto do_mfma = [&](int base) {
    uint32_t f0[4], f1[4], n0[4], n1[4];
    #pragma unroll
    for (int e = 0; e < 4; ++e) {
      const int ra = base + g32*8 + 2*e, rb = ra + 1;
      const int sa = (ra & 7) << 3, sb = (rb & 7) << 3;
      const int a0 = ra*64 + (c32 ^ sa),        b0 = rb*64 + (c32 ^ sb);
      const int a1 = ra*64 + ((32 + c32) ^ sa), b1 = rb*64 + ((32 + c32) ^ sb);
      f0[e] = (uint32_t)pF16[a0] | ((uint32_t)pF16[b0] << 16);
      f1[e] = (uint32_t)pF16[a1] | ((uint32_t)pF16[b1] << 16);
      n0[e] = (uint32_t)pN16[a0] | ((uint32_t)pN16[b0] << 16);
      n1[e] = (uint32_t)pN16[a1] | ((uint32_t)pN16[b1] << 16);
    }
    uint4 A0 = make_uint4(f0[0], f0[1], f0[2], f0[3]);
    uint4 A1 = make_uint4(f1[0], f1[1], f1[2], f1[3]);
    uint4 B0 = make_uint4(n0[0], n0[1], n0[2], n0[3]);
    uint4 B1 = make_uint4(n1[0], n1[1], n1[2], n1[3]);
    aD00 = mf(A0, B0, aD00);
    aD01 = mf(A0, B1, aD01);
    aD10 = mf(A1, B0, aD10);
    aD11 = mf(A1, B1, aD11);
  };

  // B-MFMAs consuming the LDS-staged qa fragments (pure LDS reads)
#define QALDS_B(ACC) do {                                              \
    _Pragma("unroll")                                                  \
    for (int ks = 0; ks < 4; ++ks) {                                   \
      uint4 qh_ = *(uint4*)&qabuf[(ks*2+0)*256 + lane*4];              \
      uint4 ql_ = *(uint4*)&qabuf[(ks*2+1)*256 + lane*4];              \
      uint4 Ah_ = *(uint4*)&fkFrag[((ks*2+0)*64 + lane)*4];            \
      uint4 Al_ = *(uint4*)&fkFrag[((ks*2+1)*64 + lane)*4];            \
      ACC = mf(Ah_, qh_, ACC); ACC = mf(Ah_, ql_, ACC); ACC = mf(Al_, qh_, ACC); \
    } } while(0)

#define ELEM(T2, ACU, ACW) do {                                        \
    unsigned short* rowF_ = pF16 + c32*64;                             \
    unsigned short* rowN_ = pN16 + c32*64;                             \
    const int sx_ = (c32 & 7) << 3;                                    \
    _Pragma("unroll")                                                  \
    for (int rq = 0; rq < 4; ++rq) {                                   \
      uint32_t pf_[4], pn_[4];                                         \
      _Pragma("unroll")                                                \
      for (int i = 0; i < 4; ++i) {                                    \
        const int r = rq*4 + i;                                        \
        float upd = ACU[r];                                            \
        float wx  = ACW[r];                                            \
        float wp  = __builtin_amdgcn_rcpf(1.f + __expf(-wx));          \
        float mv  = F4C(M_[(T2)*4 + rq], i);                           \
        float av  = F4C(E_[rq & 1], i);                                \
        float nm  = fmaf(wp, upd - mv, mv);                            \
        float fv  = fmaxf(nm + av, 0.f);                               \
        n2a[(T2)*16 + r] += fv;                                        \
        pn_[i] = bf16rne(nm);                                          \
        pf_[i] = bf16rne(fv);                                          \
      }                                                                \
      if (rq == 1) { E_[0] = *(const float4*)(ap0 + (T2)*32 + 16 + g32*4);      \
                     E_[1] = *(const float4*)(ap0 + (T2)*32 + 16 + g32*4 + 8); }\
      const int col = (32*(T2) + 8*rq + 4*g32) ^ sx_;                  \
      *(uint2*)&rowF_[col] = make_uint2(pf_[0] | (pf_[1]<<16), pf_[2] | (pf_[3]<<16)); \
      *(uint2*)&rowN_[col] = make_uint2(pn_[0] | (pn_[1]<<16), pn_[2] | (pn_[3]<<16)); \
    } } while(0)

  // ---- prologue: stage qa(0), B(0), stage qa(1), M(0) ----
  f32x16 aBcur = Zv, aBnext;
  float4 M_[8];
  stage_qa(wave*16 + 0);
  asm volatile("s_waitcnt vmcnt(0)" ::: "memory");
  __builtin_amdgcn_sched_barrier(0);
  QALDS_B(aBcur);
  stage_qa(wave*16 + 1);
  #pragma unroll
  for (int k = 0; k < 8; ++k) M_[k] = *(const float4*)(mRow0 + k*8 + g32*4);

  #pragma unroll 1
  for (int ss = 0; ss < 16; ++ss) {
    asm volatile("" ::: "memory");

    // ---- 1. finish B(ss): S, den; rden folded into S-fragment ----
    float s0 = aBcur[0], s1 = aBcur[1], s2 = aBcur[2], s3 = aBcur[3];
    float own = (s0 + s1) + (s2 + s3);
    float den = own + __shfl_xor(own, 32) + EPSF;
    float rden = __builtin_amdgcn_rcpf(den);
    float p0 = __shfl_xor(s0, 32), p1 = __shfl_xor(s1, 32),
          p2 = __shfl_xor(s2, 32), p3 = __shfl_xor(s3, 32);
    float rm = (g32 == 0) ? rden : 0.f;
    uint32_t sp[8] = { packsplit(s0*rm), packsplit(s1*rm), packsplit(s2*rm), packsplit(s3*rm),
                       packsplit(p0*rm), packsplit(p1*rm), packsplit(p2*rm), packsplit(p3*rm) };
    uint4 Sh = mkfrag8(sp, SELHI), Sl = mkfrag8(sp, SELLO);

    // ---- 2. C-MFMAs, first half (e-tiles 0 and 2) ----
    f32x16 aC0 = Zv, aC2 = Zv;
    {
      uint4 Vh, Vl;
      Vh = *(uint4*)&vFrag[(0*64 + lane)*4]; Vl = *(uint4*)&vFrag[(1*64 + lane)*4];
      aC0 = mf(Vh, Sh, aC0); aC0 = mf(Vh, Sl, aC0); aC0 = mf(Vl, Sh, aC0);
      Vh = *(uint4*)&vFrag[(4*64 + lane)*4]; Vl = *(uint4*)&vFrag[(5*64 + lane)*4];
      aC2 = mf(Vh, Sh, aC2); aC2 = mf(Vh, Sl, aC2); aC2 = mf(Vl, Sh, aC2);
    }

    // ---- 3. pipeline: B(ss+1) from LDS-staged qa; then stage qa(ss+2) ----
    aBnext = Zv;
    if (ss < 15) QALDS_B(aBnext);
    if (ss < 14) stage_qa(wave*16 + ss + 2);

    // ---- 4. ELEM half 0 ----
    const float* ap0 = aRow0 + (size_t)ss * 2048;
    float4 E_[2];
    E_[0] = *(const float4*)(ap0 + g32*4);
    E_[1] = *(const float4*)(ap0 + g32*4 + 8);
    ELEM(0, aC0, aC2);

    // ---- 5. C-MFMAs, second half (e-tiles 1 and 3) ----
    f32x16 aC1 = Zv, aC3 = Zv;
    {
      uint4 Vh, Vl;
      Vh = *(uint4*)&vFrag[(2*64 + lane)*4]; Vl = *(uint4*)&vFrag[(3*64 + lane)*4];
      aC1 = mf(Vh, Sh, aC1); aC1 = mf(Vh, Sl, aC1); aC1 = mf(Vl, Sh, aC1);
      Vh = *(uint4*)&vFrag[(6*64 + lane)*4]; Vl = *(uint4*)&vFrag[(7*64 + lane)*4];
      aC3 = mf(Vh, Sh, aC3); aC3 = mf(Vh, Sl, aC3); aC3 = mf(Vl, Sh, aC3);
    }

    // ---- 6. M_[0..3] <- ss+1 (HBM stream) ----
    if (ss < 15) {
      const float* mp = mRow0 + (size_t)(ss+1) * 2048;
      #pragma unroll
      for (int k = 0; k < 4; ++k) M_[k] = *(const float4*)(mp + k*8 + g32*4);
    }

    // ---- 7. ELEM half 1 ----
    E_[0] = *(const float4*)(ap0 + 32 + g32*4);
    E_[1] = *(const float4*)(ap0 + 32 + g32*4 + 8);
    ELEM(1, aC1, aC3);

    // ---- 8. M_[4..7] <- ss+1 ----
    if (ss < 15) {
      const float* mp = mRow0 + (size_t)(ss+1) * 2048;
      #pragma unroll
      for (int k = 4; k < 8; ++k) M_[k] = *(const float4*)(mp + k*8 + g32*4);
    }

    // ---- 9. phase D: both 16-row chunks (DS + MFMA only) ----
    asm volatile("" ::: "memory");
    do_mfma(0);
    do_mfma(16);

    aBcur = aBnext;
  }

  // ================= epilogue =================
  __syncthreads();

  float* n2stageF = (float*)SH;            // [4][64]
  float* norm2F   = ((float*)SH) + 256;    // [64]
  float* den2F    = ((float*)SH) + 320;    // [8]
  float* stageF   = (float*)pkbase;        // [4][16][66] (pk+qa overlay)
  const float* fqg = proj + (size_t)b * 2048 + 1536;

  #pragma unroll
  for (int k = 0; k < 32; ++k) {
    float v = n2a[k];
    v += __shfl_xor(v, 1); v += __shfl_xor(v, 2); v += __shfl_xor(v, 4);
    v += __shfl_xor(v, 8); v += __shfl_xor(v, 16);
    n2a[k] = v;
  }
  if (c32 == 0) {
    #pragma unroll
    for (int t2 = 0; t2 < 2; ++t2)
      #pragma unroll
      for (int r = 0; r < 16; ++r) {
        const int j = 32*t2 + 8*(r>>2) + (r&3) + 4*g32;
        n2stageF[wave*64 + j] = n2a[t2*16 + r];
      }
  }
  __syncthreads();
  if (tid < 64)
    norm2F[tid] = (n2stageF[tid] + n2stageF[64+tid]) + (n2stageF[128+tid] + n2stageF[192+tid]);
  __syncthreads();
  if (tid < 8) {
    float s = 0.f;
    for (int d = 0; d < 64; ++d) s = fmaf(fqg[tid*64 + d], norm2F[d], s);
    den2F[tid] = s + EPSF;
  }

  const int hh = tid >> 5;
  const int ee = (tid & 31) * 2;
  float num2a = 0.f, num2b = 0.f;
  #pragma unroll
  for (int p = 0; p < 4; ++p) {
    const int ti = p >> 1, rh = p & 1;
    #pragma unroll
    for (int q = 0; q < 8; ++q) {
      const int rr = (q & 3) + 8*((q >> 2) & 1) + 4*g32;
      const int r = rh*8 + q;
      float v0 = (ti == 0) ? aD00[r] : aD10[r];
      float v1 = (ti == 0) ? aD01[r] : aD11[r];
      stageF[wave*1056 + rr*66 + c32]      = v0;
      stageF[wave*1056 + rr*66 + 32 + c32] = v1;
    }
    __syncthreads();
    #pragma unroll 8
    for (int dl = 0; dl < 16; ++dl) {
      float2 q0 = *(const float2*)&stageF[0*1056 + dl*66 + ee];
      float2 q1 = *(const float2*)&stageF[1*1056 + dl*66 + ee];
      float2 q2 = *(const float2*)&stageF[2*1056 + dl*66 + ee];
      float2 q3 = *(const float2*)&stageF[3*1056 + dl*66 + ee];
      float v0 = (q0.x + q1.x) + (q2.x + q3.x);
      float v1 = (q0.y + q1.y) + (q2.y + q3.y);
      float fv = fqg[hh*64 + p*16 + dl];
      num2a = fmaf(fv, v0, num2a);
      num2b = fmaf(fv, v1, num2b);
    }
    __syncthreads();
  }
  float rd2 = __builtin_amdgcn_rcpf(den2F[hh]);
  {
    uint32_t pa = packsplit(num2a * rd2);
    uint32_t pb = packsplit(num2b * rd2);
    const int w32 = b*256 + hh*32 + (ee >> 1);
    attnHi[w32] = __builtin_amdgcn_perm(pb, pa, SELHI);
    attnLo[w32] = __builtin_amdgcn_perm(pb, pa, SELLO);
  }
#undef ELEM
#undef QALDS_B
}

// =====================================================================
// Kernel 3: out = attn @ Wm + bm via MFMA.
// =====================================================================
__global__ __launch_bounds__(256) void out_mfma_kernel(
    const uint32_t* __restrict__ attnHi, const uint32_t* __restrict__ attnLo,
    const uint32_t* __restrict__ wmFrag, const float* __restrict__ bm,
    float* __restrict__ out)
{
  __shared__ float red[3][64][16];
  const int tid = threadIdx.x;
  const int wave = tid >> 6, lane = tid & 63;
  const int g32 = lane >> 5, c32 = lane & 31;
  const int rt = blockIdx.x >> 5, ct = blockIdx.x & 31;

  f32x16 acc;
  #pragma unroll
  for (int r = 0; r < 16; ++r) acc[r] = 0.f;

  const uint32_t* ah = attnHi + (size_t)(rt*32 + c32)*256 + g32*4;
  const uint32_t* al = attnLo + (size_t)(rt*32 + c32)*256 + g32*4;
  const uint32_t* wb = wmFrag + (size_t)ct*256 + lane*4;

  #pragma unroll
  for (int k8 = 0; k8 < 8; ++k8) {
    const int ks = wave*8 + k8;
    uint4 Ah = *(const uint4*)(ah + ks*8);
    uint4 Al = *(const uint4*)(al + ks*8);
    uint4 Bh = *(const uint4*)(wb + (size_t)(ks*2+0)*32*256);
    uint4 Bl = *(const uint4*)(wb + (size_t)(ks*2+1)*32*256);
    acc = mf(Ah, Bh, acc);
    acc = mf(Ah, Bl, acc);
    acc = mf(Al, Bh, acc);
  }

  if (wave) {
    #pragma unroll
    for (int r = 0; r < 16; ++r) red[wave-1][lane][r] = acc[r];
  }
  __syncthreads();
  if (wave == 0) {
    const int col = ct*32 + c32;
    const float bvv = bm[col];
    #pragma unroll
    for (int r = 0; r < 16; ++r) {
      const int m = rt*32 + (r & 3) + 8*(r >> 2) + 4*g32;
      float v = acc[r] + (red[0][lane][r] + red[1][lane][r]) + red[2][lane][r] + bvv;
      out[(size_t)m * 1024 + col] = v;
    }
  }
}

extern "C" void kernel_launch(void* const* d_in, const int* in_sizes, int n_in,
                              void* d_out, int out_size, void* d_ws, size_t ws_size,
                              hipStream_t stream)
{
  const float* x    = (const float*)d_in[0];
  const float* mem  = (const float*)d_in[1];
  const float* addr = (const float*)d_in[2];
  const float* Wk   = (const float*)d_in[3];
  const float* bk   = (const float*)d_in[4];
  const float* Wv   = (const float*)d_in[5];
  const float* bv   = (const float*)d_in[6];
  const float* Wq   = (const float*)d_in[7];
  const float* bq   = (const float*)d_in[8];
  const float* Wm   = (const float*)d_in[9];
  const float* bm   = (const float*)d_in[10];
  float* out  = (float*)d_out;
  float* ws   = (float*)d_ws;
  float* proj = ws;                                         // 4 MB
  uint32_t* qaF    = (uint32_t*)(proj + (size_t)512*2048);  // 0.5 MB
  uint32_t* wFrag  = qaF + 131072;                          // 8 MB
  uint32_t* xFrag  = wFrag + 2097152;                       // 2 MB
  uint32_t* wmFrag = xFrag + 524288;                        // 2 MB
  uint32_t* attnHi = wmFrag + 524288;                       // 0.5 MB
  uint32_t* attnLo = attnHi + 131072;                       // 0.5 MB

  hipLaunchKernelGGL(pack_all_kernel, dim3(6208), dim3(64), 0, stream,
                     addr, x, Wk, Wv, Wq, Wm, qaF, xFrag, wFrag, wmFrag);
  hipLaunchKernelGGL(proj_mfma_kernel, dim3(512), dim3(256), 0, stream,
                     xFrag, wFrag, bk, bv, bq, proj);
  hipLaunchKernelGGL(fused_mem_kernel, dim3(512), dim3(256), 0, stream,
                     mem, addr, proj, qaF, attnHi, attnLo);
  hipLaunchKernelGGL(out_mfma_kernel, dim3(512), dim3(256), 0, stream,
                     attnHi, attnLo, wmFrag, bm, out);
}